// Round 17
// baseline (109.460 us; speedup 1.0000x reference)
//
#include <hip/hip_runtime.h>
#include <hip/hip_fp16.h>

#define NUSERS 100000
#define NITEMS 50000
#define EMB 64
#define BROWS 256       // rows per bucket
#define CHUNK 8192      // edges per block in scatter pass (= 256 threads x 32 edges, registers)
#define MAXB 512        // max buckets (user: 391, item: 196)
#define CAP  4096       // padded bucket capacity (mean ~3072, ~18 sigma headroom)
#define NTOH 1024       // tohalf rider blocks inside build1 (pathA)
#define NB_U ((NUSERS + BROWS - 1) / BROWS)   // 391
#define NB_I ((NITEMS + BROWS - 1) / BROWS)   // 196

// packed pair: (local_row << 20) | col   (local_row < 256, col < 2^17)

// ---- launch 1: bucketed scatter (32 edges/thread in registers) + unscaled
//      f32->f16 conversion riders (pathA: Wh disjoint from pairs) ----
__global__ void build1_kernel(const int* __restrict__ rowU, const int* __restrict__ rowI,
                              unsigned* __restrict__ bcntU, unsigned* __restrict__ bcntI,
                              unsigned* __restrict__ pairsU, unsigned* __restrict__ pairsI,
                              const float* __restrict__ WU, const float* __restrict__ WI,
                              __half* __restrict__ WhU, __half* __restrict__ WhI,
                              int EU, int EI, int gbU, int gbTot) {
    __shared__ unsigned h[MAXB];
    __shared__ unsigned base[MAXB];
    int t = threadIdx.x;
    if ((int)blockIdx.x >= gbTot) {
        // rider: unscaled f32 -> f16 stream conversion (independent of scatter)
        int nt = (int)gridDim.x - gbTot;
        const int T4U = NUSERS * (EMB / 4), T4I = NITEMS * (EMB / 4);
        for (int i = ((int)blockIdx.x - gbTot) * 256 + t; i < T4U + T4I; i += nt * 256) {
            const float4* W; __half2* Wh2; int idx;
            if (i < T4U) { W = (const float4*)WU; Wh2 = (__half2*)WhU; idx = i; }
            else         { W = (const float4*)WI; Wh2 = (__half2*)WhI; idx = i - T4U; }
            float4 w = W[idx];
            Wh2[2 * idx]     = __floats2half2_rn(w.x, w.y);
            Wh2[2 * idx + 1] = __floats2half2_rn(w.z, w.w);
        }
        return;
    }
    const int* row; const int* col; unsigned* bcnt; unsigned* pairs; int E, blk;
    if ((int)blockIdx.x < gbU) { row = rowU; col = rowU + EU; bcnt = bcntU; pairs = pairsU; E = EU; blk = blockIdx.x; }
    else                       { row = rowI; col = rowI + EI; bcnt = bcntI; pairs = pairsI; E = EI; blk = blockIdx.x - gbU; }
    for (int i = t; i < MAXB; i += 256) h[i] = 0;
    __syncthreads();
    int lo = blk * CHUNK, hi = min(lo + CHUNK, E);
    int m = hi - lo;
    int m4 = m >> 2;                       // number of full int4 groups (<= 2048)
    const int4* r4 = (const int4*)(row + lo);
    int4 rr[8];
    int  ng = 0;
    #pragma unroll
    for (int j = 0; j < 8; j++) {
        int i = t + j * 256;
        if (i < m4) {
            rr[j] = r4[i];
            ng = j + 1;
            atomicAdd(&h[rr[j].x >> 8], 1u);
            atomicAdd(&h[rr[j].y >> 8], 1u);
            atomicAdd(&h[rr[j].z >> 8], 1u);
            atomicAdd(&h[rr[j].w >> 8], 1u);
        }
    }
    int rtail = 0;
    if (t < (m & 3)) {
        rtail = row[lo + (m4 << 2) + t];
        atomicAdd(&h[rtail >> 8], 1u);
    }
    __syncthreads();
    for (int i = t; i < MAXB; i += 256) {
        unsigned cnt = h[i];
        base[i] = cnt ? ((unsigned)i * CAP + atomicAdd(&bcnt[i], cnt)) : 0u;
        h[i] = 0;
    }
    __syncthreads();
    const int4* c4 = (const int4*)(col + lo);
    #pragma unroll
    for (int j = 0; j < 8; j++) {
        if (j < ng) {
            int i = t + j * 256;
            int4 r = rr[j];
            int4 c = c4[i];
            int b0 = r.x >> 8, b1 = r.y >> 8, b2 = r.z >> 8, b3 = r.w >> 8;
            unsigned p0 = base[b0] + atomicAdd(&h[b0], 1u);
            unsigned p1 = base[b1] + atomicAdd(&h[b1], 1u);
            unsigned p2 = base[b2] + atomicAdd(&h[b2], 1u);
            unsigned p3 = base[b3] + atomicAdd(&h[b3], 1u);
            pairs[p0] = ((unsigned)(r.x & 255) << 20) | (unsigned)c.x;
            pairs[p1] = ((unsigned)(r.y & 255) << 20) | (unsigned)c.y;
            pairs[p2] = ((unsigned)(r.z & 255) << 20) | (unsigned)c.z;
            pairs[p3] = ((unsigned)(r.w & 255) << 20) | (unsigned)c.w;
        }
    }
    if (t < (m & 3)) {
        int c = col[lo + (m4 << 2) + t];
        int b0 = rtail >> 8;
        unsigned p = base[b0] + atomicAdd(&h[b0], 1u);
        pairs[p] = ((unsigned)(rtail & 255) << 20) | (unsigned)c;
    }
}

// ---- launch 2: per-bucket degree + inv + wave-scan + base alloc + fill
//      (pairs held in registers, no LDS stage; no conversion tail) ----
__global__ void bprep_kernel(const unsigned* __restrict__ bcntU, const unsigned* __restrict__ bcntI,
                             const unsigned* __restrict__ pairsU, const unsigned* __restrict__ pairsI,
                             uint2* __restrict__ odU, uint2* __restrict__ odI,
                             float* __restrict__ invU, float* __restrict__ invI,
                             int* __restrict__ colsU, int* __restrict__ colsI,
                             unsigned* __restrict__ totU, unsigned* __restrict__ totI) {
    __shared__ unsigned d[BROWS];
    __shared__ unsigned cur[BROWS];
    __shared__ unsigned wsum[4];
    __shared__ unsigned sbase;
    const unsigned* bcnt; const unsigned* pairs; uint2* od; float* inv; int* cols;
    unsigned* tot; int n, b;
    if ((int)blockIdx.x < NB_U) { bcnt = bcntU; pairs = pairsU; od = odU; inv = invU; cols = colsU; tot = totU; n = NUSERS; b = blockIdx.x; }
    else                        { bcnt = bcntI; pairs = pairsI; od = odI; inv = invI; cols = colsI; tot = totI; n = NITEMS; b = blockIdx.x - NB_U; }
    int t = threadIdx.x;
    int lane = t & 63, wid = t >> 6;
    int rbase = b * BROWS;
    d[t] = 0;
    __syncthreads();
    unsigned cnt = min(bcnt[b], (unsigned)CAP);
    unsigned lo = (unsigned)b * CAP;
    unsigned cnt4 = cnt >> 2;              // full uint4 groups (<= 1024)
    const uint4* p4 = (const uint4*)(pairs + lo);
    uint4 pk[4];
    int npk = 0;
    #pragma unroll
    for (int j = 0; j < 4; j++) {
        unsigned i = t + j * 256u;
        if (i < cnt4) {
            pk[j] = p4[i];
            npk = j + 1;
            atomicAdd(&d[pk[j].x >> 20], 1u);
            atomicAdd(&d[pk[j].y >> 20], 1u);
            atomicAdd(&d[pk[j].z >> 20], 1u);
            atomicAdd(&d[pk[j].w >> 20], 1u);
        }
    }
    unsigned pkt = 0;
    if (t < (int)(cnt & 3u)) {
        pkt = pairs[lo + (cnt4 << 2) + t];
        atomicAdd(&d[pkt >> 20], 1u);
    }
    __syncthreads();
    // exclusive scan of d[] via wave shfl-scan + 4-wave combine (2 barriers)
    unsigned v0 = d[t];
    unsigned x = v0;
    #pragma unroll
    for (int off = 1; off < 64; off <<= 1) {
        unsigned y = __shfl_up(x, off, 64);
        if (lane >= off) x += y;
    }
    if (lane == 63) wsum[wid] = x;
    __syncthreads();
    unsigned wbase = 0;
    #pragma unroll
    for (int wj = 0; wj < 4; wj++) wbase += (wj < wid) ? wsum[wj] : 0u;
    if (t == 0) sbase = atomicAdd(tot, wsum[0] + wsum[1] + wsum[2] + wsum[3]);
    __syncthreads();
    unsigned running = sbase + wbase + x - v0;   // exclusive prefix
    int idx = rbase + t;
    if (idx < n) {
        od[idx] = make_uint2(running, v0);
        inv[idx] = rsqrtf((float)(v0 + 1u));
        cur[t] = running;
    }
    __syncthreads();
    #pragma unroll
    for (int j = 0; j < 4; j++) {
        if (j < npk) {
            unsigned p0 = atomicAdd(&cur[pk[j].x >> 20], 1u);
            unsigned p1 = atomicAdd(&cur[pk[j].y >> 20], 1u);
            unsigned p2 = atomicAdd(&cur[pk[j].z >> 20], 1u);
            unsigned p3 = atomicAdd(&cur[pk[j].w >> 20], 1u);
            cols[p0] = (int)(pk[j].x & 0xFFFFFu);
            cols[p1] = (int)(pk[j].y & 0xFFFFFu);
            cols[p2] = (int)(pk[j].z & 0xFFFFFu);
            cols[p3] = (int)(pk[j].w & 0xFFFFFu);
        }
    }
    if (t < (int)(cnt & 3u)) {
        unsigned p = atomicAdd(&cur[pkt >> 20], 1u);
        cols[p] = (int)(pkt & 0xFFFFFu);
    }
}

// ---- standalone unscaled f32->f16 (pathB: Wh overlays dead pairs, runs after bprep) ----
__global__ void tohalf_kernel(const float* __restrict__ WU, const float* __restrict__ WI,
                              __half* __restrict__ WhU, __half* __restrict__ WhI) {
    const int T4U = NUSERS * (EMB / 4), T4I = NITEMS * (EMB / 4);
    for (int i = blockIdx.x * 256 + threadIdx.x; i < T4U + T4I; i += gridDim.x * 256) {
        const float4* W; __half2* Wh2; int idx;
        if (i < T4U) { W = (const float4*)WU; Wh2 = (__half2*)WhU; idx = i; }
        else         { W = (const float4*)WI; Wh2 = (__half2*)WhI; idx = i - T4U; }
        float4 w = W[idx];
        Wh2[2 * idx]     = __floats2half2_rn(w.x, w.y);
        Wh2[2 * idx + 1] = __floats2half2_rn(w.z, w.w);
    }
}

__device__ __forceinline__ void accs(float* acc, float4 f, float ic) {
    const __half2* h = (const __half2*)&f;
    #pragma unroll
    for (int j = 0; j < 4; j++) {
        float2 tv = __half22float2(h[j]);
        acc[2 * j]     += tv.x * ic;
        acc[2 * j + 1] += tv.y * ic;
    }
}

// ---- gather, unscaled f16 + inv[c]: 8 lanes/row, 8 sequential rows/wave, 4-way unroll ----
__global__ void gather2h_kernel(const uint2* __restrict__ odU, const uint2* __restrict__ odI,
                                const int* __restrict__ colsU, const int* __restrict__ colsI,
                                const __half* __restrict__ WhU, const __half* __restrict__ WhI,
                                const float* __restrict__ bU, const float* __restrict__ bI,
                                const float* __restrict__ invU, const float* __restrict__ invI,
                                float* __restrict__ outU, float* __restrict__ outI, int ggU) {
    const uint2* od; const int* cols; const __half* Wh; const float* bb; const float* inv;
    float* out; int n, r0;
    if ((int)blockIdx.x < ggU) { od = odU; cols = colsU; Wh = WhU; bb = bU; inv = invU; out = outU; n = NUSERS; r0 = blockIdx.x * 32; }
    else                       { od = odI; cols = colsI; Wh = WhI; bb = bI; inv = invI; out = outI; n = NITEMS; r0 = (blockIdx.x - ggU) * 32; }
    int r = r0 + (threadIdx.x >> 3);
    if (r >= n) return;
    int d8 = threadIdx.x & 7;
    uint2 o = od[r];
    unsigned k = o.x, end = o.x + o.y;
    const __half* wb = Wh + d8 * 8;
    float acc[8] = {0.f, 0.f, 0.f, 0.f, 0.f, 0.f, 0.f, 0.f};
    for (; k + 4 <= end; k += 4) {
        int c0 = cols[k];
        int c1 = cols[k + 1];
        int c2 = cols[k + 2];
        int c3 = cols[k + 3];
        float i0 = inv[c0], i1 = inv[c1], i2 = inv[c2], i3 = inv[c3];
        float4 f0 = *(const float4*)(wb + (size_t)c0 * EMB);
        float4 f1 = *(const float4*)(wb + (size_t)c1 * EMB);
        float4 f2 = *(const float4*)(wb + (size_t)c2 * EMB);
        float4 f3 = *(const float4*)(wb + (size_t)c3 * EMB);
        accs(acc, f0, i0); accs(acc, f1, i1); accs(acc, f2, i2); accs(acc, f3, i3);
    }
    for (; k < end; ++k) {
        int c0 = cols[k];
        float i0 = inv[c0];
        float4 f0 = *(const float4*)(wb + (size_t)c0 * EMB);
        accs(acc, f0, i0);
    }
    // epilogue: out = relu((acc + W[r]*inv_r) * inv_r + b)
    float inv_r = inv[r];
    float4 fs = *(const float4*)(Wh + (size_t)r * EMB + d8 * 8);
    accs(acc, fs, inv_r);
    const float4 bv0 = *(const float4*)(bb + d8 * 8);
    const float4 bv1 = *(const float4*)(bb + d8 * 8 + 4);
    float4 o0, o1;
    o0.x = fmaxf(acc[0] * inv_r + bv0.x, 0.f);
    o0.y = fmaxf(acc[1] * inv_r + bv0.y, 0.f);
    o0.z = fmaxf(acc[2] * inv_r + bv0.z, 0.f);
    o0.w = fmaxf(acc[3] * inv_r + bv0.w, 0.f);
    o1.x = fmaxf(acc[4] * inv_r + bv1.x, 0.f);
    o1.y = fmaxf(acc[5] * inv_r + bv1.y, 0.f);
    o1.z = fmaxf(acc[6] * inv_r + bv1.z, 0.f);
    o1.w = fmaxf(acc[7] * inv_r + bv1.w, 0.f);
    *(float4*)(out + (size_t)r * EMB + d8 * 8)     = o0;
    *(float4*)(out + (size_t)r * EMB + d8 * 8 + 4) = o1;
}

// ---- f32 fallback gather (if workspace too small for any f16 copy) ----
__global__ void gather2f_kernel(const uint2* __restrict__ odU, const uint2* __restrict__ odI,
                                const int* __restrict__ colsU, const int* __restrict__ colsI,
                                const float* __restrict__ WU, const float* __restrict__ WI,
                                const float* __restrict__ bU, const float* __restrict__ bI,
                                const float* __restrict__ invU, const float* __restrict__ invI,
                                float* __restrict__ outU, float* __restrict__ outI, int ggU) {
    const uint2* od; const int* cols; const float* W; const float* bb; const float* inv;
    float* out; int n, r0;
    if ((int)blockIdx.x < ggU) { od = odU; cols = colsU; W = WU; bb = bU; inv = invU; out = outU; n = NUSERS; r0 = blockIdx.x * 32; }
    else                       { od = odI; cols = colsI; W = WI; bb = bI; inv = invI; out = outI; n = NITEMS; r0 = (blockIdx.x - ggU) * 32; }
    int r = r0 + (threadIdx.x >> 3);
    if (r >= n) return;
    int d8 = threadIdx.x & 7;
    uint2 o = od[r];
    unsigned k = o.x, end = o.x + o.y;
    const float* wb = W + d8 * 8;
    float acc[8] = {0.f, 0.f, 0.f, 0.f, 0.f, 0.f, 0.f, 0.f};
    for (; k < end; ++k) {
        int c0 = cols[k];
        float ic = inv[c0];
        float4 f0 = *(const float4*)(wb + (size_t)c0 * EMB);
        float4 f1 = *(const float4*)(wb + (size_t)c0 * EMB + 4);
        acc[0] += f0.x * ic; acc[1] += f0.y * ic; acc[2] += f0.z * ic; acc[3] += f0.w * ic;
        acc[4] += f1.x * ic; acc[5] += f1.y * ic; acc[6] += f1.z * ic; acc[7] += f1.w * ic;
    }
    float inv_r = inv[r];
    float4 s0 = *(const float4*)(W + (size_t)r * EMB + d8 * 8);
    float4 s1 = *(const float4*)(W + (size_t)r * EMB + d8 * 8 + 4);
    const float4 bv0 = *(const float4*)(bb + d8 * 8);
    const float4 bv1 = *(const float4*)(bb + d8 * 8 + 4);
    float4 o0, o1;
    o0.x = fmaxf((acc[0] + s0.x * inv_r) * inv_r + bv0.x, 0.f);
    o0.y = fmaxf((acc[1] + s0.y * inv_r) * inv_r + bv0.y, 0.f);
    o0.z = fmaxf((acc[2] + s0.z * inv_r) * inv_r + bv0.z, 0.f);
    o0.w = fmaxf((acc[3] + s0.w * inv_r) * inv_r + bv0.w, 0.f);
    o1.x = fmaxf((acc[4] + s1.x * inv_r) * inv_r + bv1.x, 0.f);
    o1.y = fmaxf((acc[5] + s1.y * inv_r) * inv_r + bv1.y, 0.f);
    o1.z = fmaxf((acc[6] + s1.z * inv_r) * inv_r + bv1.z, 0.f);
    o1.w = fmaxf((acc[7] + s1.w * inv_r) * inv_r + bv1.w, 0.f);
    *(float4*)(out + (size_t)r * EMB + d8 * 8)     = o0;
    *(float4*)(out + (size_t)r * EMB + d8 * 8 + 4) = o1;
}

extern "C" void kernel_launch(void* const* d_in, const int* in_sizes, int n_in,
                              void* d_out, int out_size, void* d_ws, size_t ws_size,
                              hipStream_t stream) {
    const int*   ue = (const int*)d_in[0];
    const int*   ie = (const int*)d_in[1];
    const float* Wu = (const float*)d_in[2];
    const float* bu = (const float*)d_in[3];
    const float* Wi = (const float*)d_in[4];
    const float* bi = (const float*)d_in[5];

    const int E_U = in_sizes[0] / 2;
    const int E_I = in_sizes[1] / 2;

    float* out_u = (float*)d_out;
    float* out_i = out_u + (size_t)NUSERS * EMB;

    // workspace layout (4-byte words)
    unsigned* w       = (unsigned*)d_ws;
    unsigned* bcnt_u  = w;            w += MAXB;     // zeroed
    unsigned* bcnt_i  = w;            w += MAXB;     // zeroed
    unsigned* tot_u   = w;            w += 1;        // zeroed
    unsigned* tot_i   = w;            w += 1;        // zeroed
    uint2*    od_u    = (uint2*)w;    w += 2 * (size_t)NUSERS;
    uint2*    od_i    = (uint2*)w;    w += 2 * (size_t)NITEMS;
    float*    inv_u   = (float*)w;    w += NUSERS;
    float*    inv_i   = (float*)w;    w += NITEMS;
    int*      cols_u  = (int*)w;      w += E_U;
    int*      cols_i  = (int*)w;      w += E_I;
    w += (size_t)(-(intptr_t)(w - (unsigned*)d_ws)) & 3;   // align to 16 B

    const size_t pairs_words = (size_t)(NB_U + NB_I) * CAP;
    const size_t wh_words    = (size_t)(NUSERS + NITEMS) * EMB / 2;
    unsigned* pairs_u = w;
    unsigned* pairs_i = w + (size_t)NB_U * CAP;
    // Path A: Wh disjoint from pairs (rider conversion inside build1 is safe).
    // Path B: Wh overlays pairs (conversion must run standalone after bprep).
    const size_t need_A = (size_t)((char*)(w + pairs_words + wh_words) - (char*)d_ws);
    const size_t need_B = (size_t)((char*)(w + (pairs_words > wh_words ? pairs_words : wh_words)) - (char*)d_ws);
    const bool pathA = (ws_size >= need_A);
    const bool pathB = (!pathA && ws_size >= need_B);
    __half* wh_u = pathA ? (__half*)(w + pairs_words) : (__half*)w;
    __half* wh_i = wh_u + (size_t)NUSERS * EMB;

    hipMemsetAsync(bcnt_u, 0, (2 * MAXB + 2) * sizeof(unsigned), stream);

    const int gb_u  = (E_U + CHUNK - 1) / CHUNK;  // 147
    const int gb_i  = (E_I + CHUNK - 1) / CHUNK;  // 74
    const int gbTot = gb_u + gb_i;
    const int gg_u  = (NUSERS + 31) / 32;         // 3125
    const int gg_i  = (NITEMS + 31) / 32;         // 1563

    if (pathA) {
        build1_kernel <<<gbTot + NTOH, 256, 0, stream>>>(ue, ie, bcnt_u, bcnt_i, pairs_u, pairs_i,
                                                         Wu, Wi, wh_u, wh_i, E_U, E_I, gb_u, gbTot);
        bprep_kernel  <<<NB_U + NB_I, 256, 0, stream>>>(bcnt_u, bcnt_i, pairs_u, pairs_i,
                                                        od_u, od_i, inv_u, inv_i,
                                                        cols_u, cols_i, tot_u, tot_i);
        gather2h_kernel<<<gg_u + gg_i, 256, 0, stream>>>(od_u, od_i, cols_u, cols_i,
                                                         wh_u, wh_i, bu, bi, inv_u, inv_i,
                                                         out_u, out_i, gg_u);
    } else if (pathB) {
        build1_kernel <<<gbTot, 256, 0, stream>>>(ue, ie, bcnt_u, bcnt_i, pairs_u, pairs_i,
                                                  Wu, Wi, wh_u, wh_i, E_U, E_I, gb_u, gbTot);
        bprep_kernel  <<<NB_U + NB_I, 256, 0, stream>>>(bcnt_u, bcnt_i, pairs_u, pairs_i,
                                                        od_u, od_i, inv_u, inv_i,
                                                        cols_u, cols_i, tot_u, tot_i);
        tohalf_kernel <<<2048, 256, 0, stream>>>(Wu, Wi, wh_u, wh_i);
        gather2h_kernel<<<gg_u + gg_i, 256, 0, stream>>>(od_u, od_i, cols_u, cols_i,
                                                         wh_u, wh_i, bu, bi, inv_u, inv_i,
                                                         out_u, out_i, gg_u);
    } else {
        build1_kernel <<<gbTot, 256, 0, stream>>>(ue, ie, bcnt_u, bcnt_i, pairs_u, pairs_i,
                                                  Wu, Wi, (__half*)nullptr, (__half*)nullptr,
                                                  E_U, E_I, gb_u, gbTot);
        bprep_kernel  <<<NB_U + NB_I, 256, 0, stream>>>(bcnt_u, bcnt_i, pairs_u, pairs_i,
                                                        od_u, od_i, inv_u, inv_i,
                                                        cols_u, cols_i, tot_u, tot_i);
        gather2f_kernel<<<gg_u + gg_i, 256, 0, stream>>>(od_u, od_i, cols_u, cols_i,
                                                         Wu, Wi, bu, bi, inv_u, inv_i,
                                                         out_u, out_i, gg_u);
    }
}

// Round 18
// 108.428 us; speedup vs baseline: 1.0095x; 1.0095x over previous
//
#include <hip/hip_runtime.h>
#include <hip/hip_fp16.h>

#define NUSERS 100000
#define NITEMS 50000
#define EMB 64
#define BROWS 256       // rows per bucket
#define CHUNK 8192      // edges per block in scatter pass (= 256 threads x 32 edges, registers)
#define MAXB 512        // max buckets (user: 391, item: 196)
#define CAP  4096       // padded bucket capacity (mean ~3072, ~18 sigma headroom)
#define NB_U ((NUSERS + BROWS - 1) / BROWS)   // 391
#define NB_I ((NITEMS + BROWS - 1) / BROWS)   // 196

// packed pair: (local_row << 20) | col   (local_row < 256, col < 2^17)

// ---- launch 1: bucketed scatter; 32 edges/thread held in registers across passes ----
__global__ void build1_kernel(const int* __restrict__ rowU, const int* __restrict__ rowI,
                              unsigned* __restrict__ bcntU, unsigned* __restrict__ bcntI,
                              unsigned* __restrict__ pairsU, unsigned* __restrict__ pairsI,
                              int EU, int EI, int gbU) {
    __shared__ unsigned h[MAXB];
    __shared__ unsigned base[MAXB];
    int t = threadIdx.x;
    const int* row; const int* col; unsigned* bcnt; unsigned* pairs; int E, blk;
    if ((int)blockIdx.x < gbU) { row = rowU; col = rowU + EU; bcnt = bcntU; pairs = pairsU; E = EU; blk = blockIdx.x; }
    else                       { row = rowI; col = rowI + EI; bcnt = bcntI; pairs = pairsI; E = EI; blk = blockIdx.x - gbU; }
    for (int i = t; i < MAXB; i += 256) h[i] = 0;
    __syncthreads();
    int lo = blk * CHUNK, hi = min(lo + CHUNK, E);
    int m = hi - lo;
    int m4 = m >> 2;                       // number of full int4 groups (<= 2048)
    const int4* r4 = (const int4*)(row + lo);
    int4 rr[8];
    int  ng = 0;
    #pragma unroll
    for (int j = 0; j < 8; j++) {
        int i = t + j * 256;
        if (i < m4) {
            rr[j] = r4[i];
            ng = j + 1;
            atomicAdd(&h[rr[j].x >> 8], 1u);
            atomicAdd(&h[rr[j].y >> 8], 1u);
            atomicAdd(&h[rr[j].z >> 8], 1u);
            atomicAdd(&h[rr[j].w >> 8], 1u);
        }
    }
    int rtail = 0;
    if (t < (m & 3)) {
        rtail = row[lo + (m4 << 2) + t];
        atomicAdd(&h[rtail >> 8], 1u);
    }
    __syncthreads();
    for (int i = t; i < MAXB; i += 256) {
        unsigned cnt = h[i];
        base[i] = cnt ? ((unsigned)i * CAP + atomicAdd(&bcnt[i], cnt)) : 0u;
        h[i] = 0;
    }
    __syncthreads();
    const int4* c4 = (const int4*)(col + lo);
    #pragma unroll
    for (int j = 0; j < 8; j++) {
        if (j < ng) {
            int i = t + j * 256;
            int4 r = rr[j];
            int4 c = c4[i];
            int b0 = r.x >> 8, b1 = r.y >> 8, b2 = r.z >> 8, b3 = r.w >> 8;
            unsigned p0 = base[b0] + atomicAdd(&h[b0], 1u);
            unsigned p1 = base[b1] + atomicAdd(&h[b1], 1u);
            unsigned p2 = base[b2] + atomicAdd(&h[b2], 1u);
            unsigned p3 = base[b3] + atomicAdd(&h[b3], 1u);
            pairs[p0] = ((unsigned)(r.x & 255) << 20) | (unsigned)c.x;
            pairs[p1] = ((unsigned)(r.y & 255) << 20) | (unsigned)c.y;
            pairs[p2] = ((unsigned)(r.z & 255) << 20) | (unsigned)c.z;
            pairs[p3] = ((unsigned)(r.w & 255) << 20) | (unsigned)c.w;
        }
    }
    if (t < (m & 3)) {
        int c = col[lo + (m4 << 2) + t];
        int b0 = rtail >> 8;
        unsigned p = base[b0] + atomicAdd(&h[b0], 1u);
        pairs[p] = ((unsigned)(rtail & 255) << 20) | (unsigned)c;
    }
}

// ---- launch 2: per-bucket degree + inv + wave-scan + base alloc, then (pathA)
//      fused prescaled W->f16 conversion (issued BEFORE fill to hide HBM latency),
//      then cols fill from register-held pairs ----
__global__ void bprep_kernel(const unsigned* __restrict__ bcntU, const unsigned* __restrict__ bcntI,
                             const unsigned* __restrict__ pairsU, const unsigned* __restrict__ pairsI,
                             uint2* __restrict__ odU, uint2* __restrict__ odI,
                             float* __restrict__ invU, float* __restrict__ invI,
                             int* __restrict__ colsU, int* __restrict__ colsI,
                             unsigned* __restrict__ totU, unsigned* __restrict__ totI,
                             const float* __restrict__ WU, const float* __restrict__ WI,
                             __half* __restrict__ WhU, __half* __restrict__ WhI,
                             int doConv) {
    __shared__ unsigned d[BROWS];
    __shared__ unsigned cur[BROWS];
    __shared__ float    invl[BROWS];
    __shared__ unsigned wsum[4];
    __shared__ unsigned sbase;
    const unsigned* bcnt; const unsigned* pairs; uint2* od; float* inv; int* cols;
    unsigned* tot; const float* W; __half* Wh; int n, b;
    if ((int)blockIdx.x < NB_U) { bcnt = bcntU; pairs = pairsU; od = odU; inv = invU; cols = colsU; tot = totU; W = WU; Wh = WhU; n = NUSERS; b = blockIdx.x; }
    else                        { bcnt = bcntI; pairs = pairsI; od = odI; inv = invI; cols = colsI; tot = totI; W = WI; Wh = WhI; n = NITEMS; b = blockIdx.x - NB_U; }
    int t = threadIdx.x;
    int lane = t & 63, wid = t >> 6;
    int rbase = b * BROWS;
    int nrows = min(BROWS, n - rbase);
    d[t] = 0;
    __syncthreads();
    unsigned cnt = min(bcnt[b], (unsigned)CAP);
    unsigned lo = (unsigned)b * CAP;
    unsigned cnt4 = cnt >> 2;              // full uint4 groups (<= 1024)
    const uint4* p4 = (const uint4*)(pairs + lo);
    uint4 pk[4];
    int npk = 0;
    #pragma unroll
    for (int j = 0; j < 4; j++) {
        unsigned i = t + j * 256u;
        if (i < cnt4) {
            pk[j] = p4[i];
            npk = j + 1;
            atomicAdd(&d[pk[j].x >> 20], 1u);
            atomicAdd(&d[pk[j].y >> 20], 1u);
            atomicAdd(&d[pk[j].z >> 20], 1u);
            atomicAdd(&d[pk[j].w >> 20], 1u);
        }
    }
    unsigned pkt = 0;
    if (t < (int)(cnt & 3u)) {
        pkt = pairs[lo + (cnt4 << 2) + t];
        atomicAdd(&d[pkt >> 20], 1u);
    }
    __syncthreads();
    // exclusive scan of d[] via wave shfl-scan + 4-wave combine (2 barriers)
    unsigned v0 = d[t];
    unsigned x = v0;
    #pragma unroll
    for (int off = 1; off < 64; off <<= 1) {
        unsigned y = __shfl_up(x, off, 64);
        if (lane >= off) x += y;
    }
    if (lane == 63) wsum[wid] = x;
    __syncthreads();
    unsigned wbase = 0;
    #pragma unroll
    for (int wj = 0; wj < 4; wj++) wbase += (wj < wid) ? wsum[wj] : 0u;
    if (t == 0) sbase = atomicAdd(tot, wsum[0] + wsum[1] + wsum[2] + wsum[3]);
    __syncthreads();
    unsigned running = sbase + wbase + x - v0;   // exclusive prefix
    float iv = rsqrtf((float)(v0 + 1u));
    int idx = rbase + t;
    if (idx < n) {
        od[idx] = make_uint2(running, v0);
        inv[idx] = iv;
        cur[t] = running;
        invl[t] = iv;
    }
    __syncthreads();
    // fused prescaled conversion FIRST: streaming W loads issue early, their HBM
    // latency hides under the fill's LDS-atomic phase below (independent work)
    if (doConv) {
        const float4* W4 = (const float4*)W + (size_t)rbase * 16;
        __half2* Wh2 = (__half2*)Wh + (size_t)rbase * 32;
        for (int i = t; i < nrows * 16; i += 256) {
            float s = invl[i >> 4];
            float4 wv = W4[i];
            Wh2[2 * i]     = __floats2half2_rn(wv.x * s, wv.y * s);
            Wh2[2 * i + 1] = __floats2half2_rn(wv.z * s, wv.w * s);
        }
    }
    // cols fill from register-held pairs via LDS cursors
    #pragma unroll
    for (int j = 0; j < 4; j++) {
        if (j < npk) {
            unsigned p0 = atomicAdd(&cur[pk[j].x >> 20], 1u);
            unsigned p1 = atomicAdd(&cur[pk[j].y >> 20], 1u);
            unsigned p2 = atomicAdd(&cur[pk[j].z >> 20], 1u);
            unsigned p3 = atomicAdd(&cur[pk[j].w >> 20], 1u);
            cols[p0] = (int)(pk[j].x & 0xFFFFFu);
            cols[p1] = (int)(pk[j].y & 0xFFFFFu);
            cols[p2] = (int)(pk[j].z & 0xFFFFFu);
            cols[p3] = (int)(pk[j].w & 0xFFFFFu);
        }
    }
    if (t < (int)(cnt & 3u)) {
        unsigned p = atomicAdd(&cur[pkt >> 20], 1u);
        cols[p] = (int)(pkt & 0xFFFFFu);
    }
}

// ---- standalone prescaled f32->f16 (pathB: Wh overlays dead pairs, runs after bprep) ----
__global__ void tohalf_kernel(const float* __restrict__ WU, const float* __restrict__ WI,
                              const float* __restrict__ invU, const float* __restrict__ invI,
                              __half* __restrict__ WhU, __half* __restrict__ WhI) {
    const int T4U = NUSERS * (EMB / 4), T4I = NITEMS * (EMB / 4);
    for (int i = blockIdx.x * 256 + threadIdx.x; i < T4U + T4I; i += gridDim.x * 256) {
        const float4* W; const float* inv; __half2* Wh2; int idx;
        if (i < T4U) { W = (const float4*)WU; inv = invU; Wh2 = (__half2*)WhU; idx = i; }
        else         { W = (const float4*)WI; inv = invI; Wh2 = (__half2*)WhI; idx = i - T4U; }
        float s = inv[idx >> 4];
        float4 w = W[idx];
        Wh2[2 * idx]     = __floats2half2_rn(w.x * s, w.y * s);
        Wh2[2 * idx + 1] = __floats2half2_rn(w.z * s, w.w * s);
    }
}

__device__ __forceinline__ void acc8(float* acc, float4 f) {
    const __half2* h = (const __half2*)&f;
    #pragma unroll
    for (int j = 0; j < 4; j++) {
        float2 tv = __half22float2(h[j]);
        acc[2 * j]     += tv.x;
        acc[2 * j + 1] += tv.y;
    }
}

// ---- gather, prescaled f16: 8 lanes/row, 8 sequential rows/wave, 4-way unroll ----
__global__ void gather2h_kernel(const uint2* __restrict__ odU, const uint2* __restrict__ odI,
                                const int* __restrict__ colsU, const int* __restrict__ colsI,
                                const __half* __restrict__ WhU, const __half* __restrict__ WhI,
                                const float* __restrict__ bU, const float* __restrict__ bI,
                                const float* __restrict__ invU, const float* __restrict__ invI,
                                float* __restrict__ outU, float* __restrict__ outI, int ggU) {
    const uint2* od; const int* cols; const __half* Wh; const float* bb; const float* inv;
    float* out; int n, r0;
    if ((int)blockIdx.x < ggU) { od = odU; cols = colsU; Wh = WhU; bb = bU; inv = invU; out = outU; n = NUSERS; r0 = blockIdx.x * 32; }
    else                       { od = odI; cols = colsI; Wh = WhI; bb = bI; inv = invI; out = outI; n = NITEMS; r0 = (blockIdx.x - ggU) * 32; }
    int r = r0 + (threadIdx.x >> 3);
    if (r >= n) return;
    int d8 = threadIdx.x & 7;
    uint2 o = od[r];
    unsigned k = o.x, end = o.x + o.y;
    const __half* wb = Wh + d8 * 8;
    float acc[8] = {0.f, 0.f, 0.f, 0.f, 0.f, 0.f, 0.f, 0.f};
    for (; k + 4 <= end; k += 4) {
        int c0 = cols[k];
        int c1 = cols[k + 1];
        int c2 = cols[k + 2];
        int c3 = cols[k + 3];
        float4 f0 = *(const float4*)(wb + (size_t)c0 * EMB);
        float4 f1 = *(const float4*)(wb + (size_t)c1 * EMB);
        float4 f2 = *(const float4*)(wb + (size_t)c2 * EMB);
        float4 f3 = *(const float4*)(wb + (size_t)c3 * EMB);
        acc8(acc, f0); acc8(acc, f1); acc8(acc, f2); acc8(acc, f3);
    }
    for (; k < end; ++k) {
        int c0 = cols[k];
        float4 f0 = *(const float4*)(wb + (size_t)c0 * EMB);
        acc8(acc, f0);
    }
    // epilogue: out = relu((acc + Wh[r]) * inv_r + b)   (Wh[r]*inv_r = W[r]*inv_r^2)
    float inv_r = inv[r];
    float4 fs = *(const float4*)(Wh + (size_t)r * EMB + d8 * 8);
    acc8(acc, fs);
    const float4 bv0 = *(const float4*)(bb + d8 * 8);
    const float4 bv1 = *(const float4*)(bb + d8 * 8 + 4);
    float4 o0, o1;
    o0.x = fmaxf(acc[0] * inv_r + bv0.x, 0.f);
    o0.y = fmaxf(acc[1] * inv_r + bv0.y, 0.f);
    o0.z = fmaxf(acc[2] * inv_r + bv0.z, 0.f);
    o0.w = fmaxf(acc[3] * inv_r + bv0.w, 0.f);
    o1.x = fmaxf(acc[4] * inv_r + bv1.x, 0.f);
    o1.y = fmaxf(acc[5] * inv_r + bv1.y, 0.f);
    o1.z = fmaxf(acc[6] * inv_r + bv1.z, 0.f);
    o1.w = fmaxf(acc[7] * inv_r + bv1.w, 0.f);
    *(float4*)(out + (size_t)r * EMB + d8 * 8)     = o0;
    *(float4*)(out + (size_t)r * EMB + d8 * 8 + 4) = o1;
}

// ---- f32 fallback gather (if workspace too small for any f16 copy) ----
__global__ void gather2f_kernel(const uint2* __restrict__ odU, const uint2* __restrict__ odI,
                                const int* __restrict__ colsU, const int* __restrict__ colsI,
                                const float* __restrict__ WU, const float* __restrict__ WI,
                                const float* __restrict__ bU, const float* __restrict__ bI,
                                const float* __restrict__ invU, const float* __restrict__ invI,
                                float* __restrict__ outU, float* __restrict__ outI, int ggU) {
    const uint2* od; const int* cols; const float* W; const float* bb; const float* inv;
    float* out; int n, r0;
    if ((int)blockIdx.x < ggU) { od = odU; cols = colsU; W = WU; bb = bU; inv = invU; out = outU; n = NUSERS; r0 = blockIdx.x * 32; }
    else                       { od = odI; cols = colsI; W = WI; bb = bI; inv = invI; out = outI; n = NITEMS; r0 = (blockIdx.x - ggU) * 32; }
    int r = r0 + (threadIdx.x >> 3);
    if (r >= n) return;
    int d8 = threadIdx.x & 7;
    uint2 o = od[r];
    unsigned k = o.x, end = o.x + o.y;
    const float* wb = W + d8 * 8;
    float acc[8] = {0.f, 0.f, 0.f, 0.f, 0.f, 0.f, 0.f, 0.f};
    for (; k < end; ++k) {
        int c0 = cols[k];
        float ic = inv[c0];
        float4 f0 = *(const float4*)(wb + (size_t)c0 * EMB);
        float4 f1 = *(const float4*)(wb + (size_t)c0 * EMB + 4);
        acc[0] += f0.x * ic; acc[1] += f0.y * ic; acc[2] += f0.z * ic; acc[3] += f0.w * ic;
        acc[4] += f1.x * ic; acc[5] += f1.y * ic; acc[6] += f1.z * ic; acc[7] += f1.w * ic;
    }
    float inv_r = inv[r];
    float4 s0 = *(const float4*)(W + (size_t)r * EMB + d8 * 8);
    float4 s1 = *(const float4*)(W + (size_t)r * EMB + d8 * 8 + 4);
    const float4 bv0 = *(const float4*)(bb + d8 * 8);
    const float4 bv1 = *(const float4*)(bb + d8 * 8 + 4);
    float4 o0, o1;
    o0.x = fmaxf((acc[0] + s0.x * inv_r) * inv_r + bv0.x, 0.f);
    o0.y = fmaxf((acc[1] + s0.y * inv_r) * inv_r + bv0.y, 0.f);
    o0.z = fmaxf((acc[2] + s0.z * inv_r) * inv_r + bv0.z, 0.f);
    o0.w = fmaxf((acc[3] + s0.w * inv_r) * inv_r + bv0.w, 0.f);
    o1.x = fmaxf((acc[4] + s1.x * inv_r) * inv_r + bv1.x, 0.f);
    o1.y = fmaxf((acc[5] + s1.y * inv_r) * inv_r + bv1.y, 0.f);
    o1.z = fmaxf((acc[6] + s1.z * inv_r) * inv_r + bv1.z, 0.f);
    o1.w = fmaxf((acc[7] + s1.w * inv_r) * inv_r + bv1.w, 0.f);
    *(float4*)(out + (size_t)r * EMB + d8 * 8)     = o0;
    *(float4*)(out + (size_t)r * EMB + d8 * 8 + 4) = o1;
}

extern "C" void kernel_launch(void* const* d_in, const int* in_sizes, int n_in,
                              void* d_out, int out_size, void* d_ws, size_t ws_size,
                              hipStream_t stream) {
    const int*   ue = (const int*)d_in[0];
    const int*   ie = (const int*)d_in[1];
    const float* Wu = (const float*)d_in[2];
    const float* bu = (const float*)d_in[3];
    const float* Wi = (const float*)d_in[4];
    const float* bi = (const float*)d_in[5];

    const int E_U = in_sizes[0] / 2;
    const int E_I = in_sizes[1] / 2;

    float* out_u = (float*)d_out;
    float* out_i = out_u + (size_t)NUSERS * EMB;

    // workspace layout (4-byte words)
    unsigned* w       = (unsigned*)d_ws;
    unsigned* bcnt_u  = w;            w += MAXB;     // zeroed
    unsigned* bcnt_i  = w;            w += MAXB;     // zeroed
    unsigned* tot_u   = w;            w += 1;        // zeroed
    unsigned* tot_i   = w;            w += 1;        // zeroed
    uint2*    od_u    = (uint2*)w;    w += 2 * (size_t)NUSERS;
    uint2*    od_i    = (uint2*)w;    w += 2 * (size_t)NITEMS;
    float*    inv_u   = (float*)w;    w += NUSERS;
    float*    inv_i   = (float*)w;    w += NITEMS;
    int*      cols_u  = (int*)w;      w += E_U;
    int*      cols_i  = (int*)w;      w += E_I;
    w += (size_t)(-(intptr_t)(w - (unsigned*)d_ws)) & 3;   // align to 16 B

    const size_t pairs_words = (size_t)(NB_U + NB_I) * CAP;
    const size_t wh_words    = (size_t)(NUSERS + NITEMS) * EMB / 2;
    unsigned* pairs_u = w;
    unsigned* pairs_i = w + (size_t)NB_U * CAP;
    // Path A: Wh disjoint from pairs (conversion fused into bprep is safe).
    // Path B: Wh overlays pairs (conversion must run standalone after bprep).
    const size_t need_A = (size_t)((char*)(w + pairs_words + wh_words) - (char*)d_ws);
    const size_t need_B = (size_t)((char*)(w + (pairs_words > wh_words ? pairs_words : wh_words)) - (char*)d_ws);
    const bool pathA = (ws_size >= need_A);
    const bool pathB = (!pathA && ws_size >= need_B);
    __half* wh_u = pathA ? (__half*)(w + pairs_words) : (__half*)w;
    __half* wh_i = wh_u + (size_t)NUSERS * EMB;

    hipMemsetAsync(bcnt_u, 0, (2 * MAXB + 2) * sizeof(unsigned), stream);

    const int gb_u  = (E_U + CHUNK - 1) / CHUNK;  // 147
    const int gb_i  = (E_I + CHUNK - 1) / CHUNK;  // 74
    const int gbTot = gb_u + gb_i;
    const int gg_u  = (NUSERS + 31) / 32;         // 3125
    const int gg_i  = (NITEMS + 31) / 32;         // 1563

    build1_kernel<<<gbTot, 256, 0, stream>>>(ue, ie, bcnt_u, bcnt_i, pairs_u, pairs_i,
                                             E_U, E_I, gb_u);
    if (pathA) {
        bprep_kernel  <<<NB_U + NB_I, 256, 0, stream>>>(bcnt_u, bcnt_i, pairs_u, pairs_i,
                                                        od_u, od_i, inv_u, inv_i,
                                                        cols_u, cols_i, tot_u, tot_i,
                                                        Wu, Wi, wh_u, wh_i, 1);
        gather2h_kernel<<<gg_u + gg_i, 256, 0, stream>>>(od_u, od_i, cols_u, cols_i,
                                                         wh_u, wh_i, bu, bi, inv_u, inv_i,
                                                         out_u, out_i, gg_u);
    } else if (pathB) {
        bprep_kernel  <<<NB_U + NB_I, 256, 0, stream>>>(bcnt_u, bcnt_i, pairs_u, pairs_i,
                                                        od_u, od_i, inv_u, inv_i,
                                                        cols_u, cols_i, tot_u, tot_i,
                                                        Wu, Wi, wh_u, wh_i, 0);
        tohalf_kernel <<<2048, 256, 0, stream>>>(Wu, Wi, inv_u, inv_i, wh_u, wh_i);
        gather2h_kernel<<<gg_u + gg_i, 256, 0, stream>>>(od_u, od_i, cols_u, cols_i,
                                                         wh_u, wh_i, bu, bi, inv_u, inv_i,
                                                         out_u, out_i, gg_u);
    } else {
        bprep_kernel  <<<NB_U + NB_I, 256, 0, stream>>>(bcnt_u, bcnt_i, pairs_u, pairs_i,
                                                        od_u, od_i, inv_u, inv_i,
                                                        cols_u, cols_i, tot_u, tot_i,
                                                        Wu, Wi, (__half*)nullptr, (__half*)nullptr, 0);
        gather2f_kernel<<<gg_u + gg_i, 256, 0, stream>>>(od_u, od_i, cols_u, cols_i,
                                                         Wu, Wi, bu, bi, inv_u, inv_i,
                                                         out_u, out_i, gg_u);
    }
}